// Round 2
// baseline (439.516 us; speedup 1.0000x reference)
//
#include <hip/hip_runtime.h>
#include <math.h>

#define CC 256
#define NN 4096
#define DD 32
#define BB 4
#define QK_SCALE 0.17677669529663687f  // 1/sqrt(32)

// ---------------------------------------------------------------------------
// Kernel 1: QKV projection.  tok[b,n,c] = x[b,c,n];  qkv = tok @ w_qkv^T + b.
// Block: (b, 64-token tile). LDS-stage x tile as [c][tok] (64 KB).
// Thread (tt = t&15 -> tokens 4tt..+3, g = t>>4 -> d = 6g..+5), c-blocked by 4.
// Q is pre-scaled by 1/sqrt(D).
// ---------------------------------------------------------------------------
__global__ __launch_bounds__(256) void qkv_kernel(
    const float* __restrict__ x, const float* __restrict__ w_qkv,
    const float* __restrict__ b_qkv, float* __restrict__ Q,
    float* __restrict__ K, float* __restrict__ V) {
  __shared__ float xs[CC * 64];  // [c][tok]
  const int t = threadIdx.x;
  const int b = blockIdx.x >> 6;
  const int n0 = (blockIdx.x & 63) << 6;
  const float* xb = x + (size_t)b * CC * NN + n0;

  {
    const int tokl = t & 63, cg = t >> 6;
    for (int i = 0; i < 64; ++i) {
      const int c = cg * 64 + i;
      xs[c * 64 + tokl] = xb[(size_t)c * NN + tokl];
    }
  }
  __syncthreads();

  const int tt = t & 15;
  const int g = t >> 4;
  float acc[6][4];
#pragma unroll
  for (int j = 0; j < 6; ++j) {
    const float bv = b_qkv[g * 6 + j];
#pragma unroll
    for (int r = 0; r < 4; ++r) acc[j][r] = bv;
  }

  for (int cb = 0; cb < CC; cb += 4) {
    float4 xv[4];
#pragma unroll
    for (int q = 0; q < 4; ++q)
      xv[q] = *(const float4*)&xs[(cb + q) * 64 + tt * 4];
#pragma unroll
    for (int j = 0; j < 6; ++j) {
      const float4 wv = *(const float4*)&w_qkv[(g * 6 + j) * CC + cb];
      acc[j][0] += wv.x * xv[0].x + wv.y * xv[1].x + wv.z * xv[2].x + wv.w * xv[3].x;
      acc[j][1] += wv.x * xv[0].y + wv.y * xv[1].y + wv.z * xv[2].y + wv.w * xv[3].y;
      acc[j][2] += wv.x * xv[0].z + wv.y * xv[1].z + wv.z * xv[2].z + wv.w * xv[3].z;
      acc[j][3] += wv.x * xv[0].w + wv.y * xv[1].w + wv.z * xv[2].w + wv.w * xv[3].w;
    }
  }

#pragma unroll
  for (int j = 0; j < 6; ++j) {
    const int d = g * 6 + j;
    float* dst;
    int dd;
    float mul = 1.0f;
    if (d < DD) { dst = Q; dd = d; mul = QK_SCALE; }
    else if (d < 2 * DD) { dst = K; dd = d - DD; }
    else { dst = V; dd = d - 2 * DD; }
#pragma unroll
    for (int r = 0; r < 4; ++r) {
      dst[((size_t)b * NN + n0 + tt * 4 + r) * DD + dd] = acc[j][r] * mul;
    }
  }
}

// ---------------------------------------------------------------------------
// Kernel 2: flash attention (fp32). Block = (b, 64-query tile), 256 threads.
// Q/K tiles in swizzled 16B-chunk LDS layout; S computed 4x4 per thread;
// online softmax fully in registers (shfl over the 16 lanes sharing a row
// block); P staged in LDS; PV accumulates 4 rows x 2 d per thread.
// ---------------------------------------------------------------------------
__global__ __launch_bounds__(256) void attn_kernel(
    const float* __restrict__ Q, const float* __restrict__ K,
    const float* __restrict__ V, float* __restrict__ O) {
  __shared__ float4 Qs[64 * 8];   // chunk pos = cb ^ ((row>>2)&7)
  __shared__ float4 Ks[64 * 8];
  __shared__ float Vs[64 * 36];   // row-major, padded
  __shared__ float Ps[64 * 68];   // row-major, padded

  const int t = threadIdx.x;
  const int b = blockIdx.x >> 6;
  const int n0 = (blockIdx.x & 63) << 6;
  const float* Qb = Q + ((size_t)b * NN + n0) * DD;
  const float* Kb = K + (size_t)b * NN * DD;
  const float* Vb = V + (size_t)b * NN * DD;

  // stage Q tile (64 rows x 32 d) once
#pragma unroll
  for (int p = 0; p < 2; ++p) {
    const int idx = t + 256 * p;
    const int row = idx >> 3, cb = idx & 7;
    Qs[row * 8 + (cb ^ ((row >> 2) & 7))] = *(const float4*)&Qb[row * DD + cb * 4];
  }

  const int ti = t >> 4;  // S rows 4ti..+3 (also O rows)
  const int tj = t & 15;  // S cols 4tj..+3 ; O cols d = 2tj..+1

  float m_run[4], l_run[4], oacc[4][2];
#pragma unroll
  for (int r = 0; r < 4; ++r) {
    m_run[r] = -INFINITY;
    l_run[r] = 0.f;
    oacc[r][0] = 0.f;
    oacc[r][1] = 0.f;
  }

  for (int kt = 0; kt < 64; ++kt) {
    __syncthreads();  // prior PV done (and Q stage on first iter)
    // stage K and V tiles
    const float* Kt = Kb + (size_t)kt * 64 * DD;
    const float* Vt = Vb + (size_t)kt * 64 * DD;
#pragma unroll
    for (int p = 0; p < 2; ++p) {
      const int idx = t + 256 * p;
      const int row = idx >> 3, cb = idx & 7;
      Ks[row * 8 + (cb ^ ((row >> 2) & 7))] = *(const float4*)&Kt[row * DD + cb * 4];
      *(float4*)&Vs[row * 36 + cb * 4] = *(const float4*)&Vt[row * DD + cb * 4];
    }
    __syncthreads();

    // S = Q K^T, 4x4 per thread
    float s[4][4];
#pragma unroll
    for (int r = 0; r < 4; ++r)
#pragma unroll
      for (int q = 0; q < 4; ++q) s[r][q] = 0.f;

#pragma unroll
    for (int cb = 0; cb < 8; ++cb) {
      float4 qv[4], kv[4];
#pragma unroll
      for (int r = 0; r < 4; ++r)
        qv[r] = Qs[(ti * 4 + r) * 8 + (cb ^ (ti & 7))];
#pragma unroll
      for (int q = 0; q < 4; ++q)
        kv[q] = Ks[(tj * 4 + q) * 8 + (cb ^ (tj & 7))];
#pragma unroll
      for (int r = 0; r < 4; ++r)
#pragma unroll
        for (int q = 0; q < 4; ++q)
          s[r][q] += qv[r].x * kv[q].x + qv[r].y * kv[q].y +
                     qv[r].z * kv[q].z + qv[r].w * kv[q].w;
    }

    // online softmax in registers; 16 lanes (tj group) share each row block
#pragma unroll
    for (int r = 0; r < 4; ++r) {
      float mx = fmaxf(fmaxf(s[r][0], s[r][1]), fmaxf(s[r][2], s[r][3]));
      mx = fmaxf(mx, __shfl_xor(mx, 1));
      mx = fmaxf(mx, __shfl_xor(mx, 2));
      mx = fmaxf(mx, __shfl_xor(mx, 4));
      mx = fmaxf(mx, __shfl_xor(mx, 8));
      const float mnew = fmaxf(m_run[r], mx);
      const float al = __expf(m_run[r] - mnew);
      m_run[r] = mnew;
      float sum = 0.f;
#pragma unroll
      for (int q = 0; q < 4; ++q) {
        const float pv = __expf(s[r][q] - mnew);
        s[r][q] = pv;
        sum += pv;
      }
      sum += __shfl_xor(sum, 1);
      sum += __shfl_xor(sum, 2);
      sum += __shfl_xor(sum, 4);
      sum += __shfl_xor(sum, 8);
      l_run[r] = l_run[r] * al + sum;
      oacc[r][0] *= al;
      oacc[r][1] *= al;
      *(float4*)&Ps[(ti * 4 + r) * 68 + tj * 4] =
          make_float4(s[r][0], s[r][1], s[r][2], s[r][3]);
    }
    __syncthreads();

    // PV: O[rows][2tj..+1] += P[rows][j] * V[j][2tj..+1]
#pragma unroll 4
    for (int jb = 0; jb < 16; ++jb) {
      float4 pv[4];
#pragma unroll
      for (int r = 0; r < 4; ++r)
        pv[r] = *(const float4*)&Ps[(ti * 4 + r) * 68 + jb * 4];
      const float2 vv0 = *(const float2*)&Vs[(jb * 4 + 0) * 36 + tj * 2];
      const float2 vv1 = *(const float2*)&Vs[(jb * 4 + 1) * 36 + tj * 2];
      const float2 vv2 = *(const float2*)&Vs[(jb * 4 + 2) * 36 + tj * 2];
      const float2 vv3 = *(const float2*)&Vs[(jb * 4 + 3) * 36 + tj * 2];
#pragma unroll
      for (int r = 0; r < 4; ++r) {
        oacc[r][0] += pv[r].x * vv0.x + pv[r].y * vv1.x + pv[r].z * vv2.x + pv[r].w * vv3.x;
        oacc[r][1] += pv[r].x * vv0.y + pv[r].y * vv1.y + pv[r].z * vv2.y + pv[r].w * vv3.y;
      }
    }
  }

  // epilogue: normalize and store
  float* Ob = O + ((size_t)b * NN + n0) * DD;
#pragma unroll
  for (int r = 0; r < 4; ++r) {
    const float inv = 1.0f / l_run[r];
    *(float2*)&Ob[(ti * 4 + r) * DD + tj * 2] =
        make_float2(oacc[r][0] * inv, oacc[r][1] * inv);
  }
}

// ---------------------------------------------------------------------------
// Kernel 3: output projection + residual.
// Thread: one token (tokl = t&63), one wave-uniform channel group (64 ch).
// O-row held in 32 registers; w_proj rows are wave-uniform -> scalar loads.
// ---------------------------------------------------------------------------
__global__ __launch_bounds__(256) void proj_kernel(
    const float* __restrict__ O, const float* __restrict__ w_proj,
    const float* __restrict__ b_proj, const float* __restrict__ x,
    float* __restrict__ out) {
  __shared__ float Os[64 * 36];
  const int t = threadIdx.x;
  const int b = blockIdx.x >> 6;
  const int n0 = (blockIdx.x & 63) << 6;
  const float* Obl = O + ((size_t)b * NN + n0) * DD;

#pragma unroll
  for (int p = 0; p < 2; ++p) {
    const int idx = t + 256 * p;
    const int row = idx >> 3, c4 = idx & 7;
    *(float4*)&Os[row * 36 + c4 * 4] = *(const float4*)&Obl[row * DD + c4 * 4];
  }
  __syncthreads();

  const int tokl = t & 63;
  const int cg = __builtin_amdgcn_readfirstlane(t >> 6);

  float ov[DD];
#pragma unroll
  for (int c4 = 0; c4 < 8; ++c4) {
    const float4 v = *(const float4*)&Os[tokl * 36 + c4 * 4];
    ov[c4 * 4 + 0] = v.x;
    ov[c4 * 4 + 1] = v.y;
    ov[c4 * 4 + 2] = v.z;
    ov[c4 * 4 + 3] = v.w;
  }

  const size_t base = (size_t)b * CC * NN + n0 + tokl;
  for (int i = 0; i < 64; ++i) {
    const int c = cg * 64 + i;
    const float* wr = &w_proj[c * DD];
    float acc = b_proj[c];
#pragma unroll
    for (int d = 0; d < DD; ++d) acc += wr[d] * ov[d];
    const size_t off = base + (size_t)c * NN;
    out[off] = acc + x[off];
  }
}

// ---------------------------------------------------------------------------
extern "C" void kernel_launch(void* const* d_in, const int* in_sizes, int n_in,
                              void* d_out, int out_size, void* d_ws, size_t ws_size,
                              hipStream_t stream) {
  const float* x      = (const float*)d_in[0];
  const float* w_qkv  = (const float*)d_in[1];
  const float* b_qkv  = (const float*)d_in[2];
  const float* w_proj = (const float*)d_in[3];
  const float* b_proj = (const float*)d_in[4];
  float* out = (float*)d_out;

  float* ws = (float*)d_ws;
  const size_t BND = (size_t)BB * NN * DD;  // 524288 floats
  float* Q = ws;
  float* K = ws + BND;
  float* V = ws + 2 * BND;
  float* O = ws + 3 * BND;  // 8 MB total workspace use

  const dim3 grid(BB * (NN / 64));  // 256 blocks
  const dim3 block(256);
  qkv_kernel<<<grid, block, 0, stream>>>(x, w_qkv, b_qkv, Q, K, V);
  attn_kernel<<<grid, block, 0, stream>>>(Q, K, V, O);
  proj_kernel<<<grid, block, 0, stream>>>(O, w_proj, b_proj, x, out);
}

// Round 5
// 243.718 us; speedup vs baseline: 1.8034x; 1.8034x over previous
//
#include <hip/hip_runtime.h>
#include <math.h>

#define CC 256
#define NN 4096
#define DD 32
#define BB 4
#define QK_SCALE 0.17677669529663687f  // 1/sqrt(32)

typedef short bf16x8 __attribute__((ext_vector_type(8)));
typedef float f32x4 __attribute__((ext_vector_type(4)));

__device__ __forceinline__ short f2bf(float f) {  // RNE float->bf16
  unsigned u = __builtin_bit_cast(unsigned, f);
  u += 0x7fffu + ((u >> 16) & 1u);
  return (short)(u >> 16);
}

__device__ __forceinline__ void async16(const short* g, short* l) {
  __builtin_amdgcn_global_load_lds(
      (const __attribute__((address_space(1))) void*)g,
      (__attribute__((address_space(3))) void*)l, 16, 0, 0);
}

// ---------------------------------------------------------------------------
// Kernel 1: QKV projection -> bf16 Q (pre-scaled) [B][N][32], K [B][N][32],
// V transposed [B][32][N].
// ---------------------------------------------------------------------------
__global__ __launch_bounds__(256) void qkv_kernel(
    const float* __restrict__ x, const float* __restrict__ w_qkv,
    const float* __restrict__ b_qkv, short* __restrict__ Qb,
    short* __restrict__ Kb, short* __restrict__ Vt) {
  __shared__ float xs[CC * 64];  // [c][tok]
  const int t = threadIdx.x;
  const int b = blockIdx.x >> 6;
  const int n0 = (blockIdx.x & 63) << 6;
  const float* xb = x + (size_t)b * CC * NN + n0;

  {
    const int tokl = t & 63, cg = t >> 6;
    for (int i = 0; i < 64; ++i) {
      const int c = cg * 64 + i;
      xs[c * 64 + tokl] = xb[(size_t)c * NN + tokl];
    }
  }
  __syncthreads();

  const int tt = t & 15;
  const int g = t >> 4;
  float acc[6][4];
#pragma unroll
  for (int j = 0; j < 6; ++j) {
    const float bv = b_qkv[g * 6 + j];
#pragma unroll
    for (int r = 0; r < 4; ++r) acc[j][r] = bv;
  }

  for (int cb = 0; cb < CC; cb += 4) {
    float4 xv[4];
#pragma unroll
    for (int q = 0; q < 4; ++q)
      xv[q] = *(const float4*)&xs[(cb + q) * 64 + tt * 4];
#pragma unroll
    for (int j = 0; j < 6; ++j) {
      const float4 wv = *(const float4*)&w_qkv[(g * 6 + j) * CC + cb];
      acc[j][0] += wv.x * xv[0].x + wv.y * xv[1].x + wv.z * xv[2].x + wv.w * xv[3].x;
      acc[j][1] += wv.x * xv[0].y + wv.y * xv[1].y + wv.z * xv[2].y + wv.w * xv[3].y;
      acc[j][2] += wv.x * xv[0].z + wv.y * xv[1].z + wv.z * xv[2].z + wv.w * xv[3].z;
      acc[j][3] += wv.x * xv[0].w + wv.y * xv[1].w + wv.z * xv[2].w + wv.w * xv[3].w;
    }
  }

#pragma unroll
  for (int j = 0; j < 6; ++j) {
    const int d = g * 6 + j;
#pragma unroll
    for (int r = 0; r < 4; ++r) {
      const int tok = n0 + tt * 4 + r;
      const float v = acc[j][r];
      if (d < DD)
        Qb[((size_t)b * NN + tok) * DD + d] = f2bf(v * QK_SCALE);
      else if (d < 2 * DD)
        Kb[((size_t)b * NN + tok) * DD + (d - DD)] = f2bf(v);
      else
        Vt[(size_t)b * DD * NN + (size_t)(d - 2 * DD) * NN + tok] = f2bf(v);
    }
  }
}

// ---------------------------------------------------------------------------
// Kernel 2: flash attention, bf16 MFMA 16x16x32. Block = (b, 64 q rows),
// 4 waves x 16 rows. KBLK=64, K/V double-buffered via global_load_lds with
// pre-swizzled global sources (LDS dest must stay linear).
//
// LDS layouts (16B chunks, XOR-swizzled to kill b128 row-stride conflicts):
//  Ks: rows R=key>>1 (128B): slot(key,hic) = ((key&1)*4+hic) ^ (R&7)
//  Vs: rows d (128B of 64 keys): slot = chunk ^ (d&7)
//  Ps: per-wave [16 q][64 k] bf16: slot = chunk ^ (q&7)
// MFMA frag maps (A row / B col = lane&15, k = (lane>>4)*8 + j; QK^T and PV
// each load both operands with the same map -> k-permutation cancels).
// C/D: col = lane&15, row = (lane>>4)*4 + reg  [verified layout].
// ---------------------------------------------------------------------------
__global__ __launch_bounds__(256) void attn_kernel(
    const short* __restrict__ Qb, const short* __restrict__ Kb,
    const short* __restrict__ Vt, float* __restrict__ O) {
  __shared__ short Ks[2][2048];  // 4 KB per buf
  __shared__ short Vs[2][2048];
  __shared__ short Ps[4][1024];  // per-wave P tile

  const int t = threadIdx.x;
  const int b = blockIdx.x >> 6;
  const int n0 = (blockIdx.x & 63) << 6;
  const int w = t >> 6;
  const int lane = t & 63;
  const int lo = lane & 15, hi = lane >> 4;

  // staging source addresses (global side carries the inverse swizzle)
  const short* Kbase;
  {
    const int r = t >> 3, c = t & 7;
    const int u = c ^ (r & 7);
    const int key = 2 * r + (u >> 2), hic = u & 3;
    Kbase = Kb + (size_t)b * NN * DD + key * DD + hic * 8;
  }
  const short* Vbase;
  {
    const int r = t >> 3, c = t & 7;
    const int cs = c ^ (r & 7);
    Vbase = Vt + (size_t)b * DD * NN + (size_t)r * NN + cs * 8;
  }

  // Q A-frag: row = lane&15, k = hi*8..+7 (one 16B global load, held all tiles)
  const bf16x8 qf =
      *(const bf16x8*)(Qb + ((size_t)b * NN + n0 + w * 16 + lo) * DD + hi * 8);

  f32x4 oacc[2];
  float m_run[4], l_run[4];
#pragma unroll
  for (int r = 0; r < 4; ++r) {
    m_run[r] = -1e30f;
    l_run[r] = 0.f;
    oacc[0][r] = 0.f;
    oacc[1][r] = 0.f;
  }

  // prologue: stage tile 0 into buffer 0
  async16(Kbase, &Ks[0][t * 8]);
  async16(Vbase, &Vs[0][t * 8]);
  __syncthreads();

  int cur = 0;
  for (int kt = 0; kt < 64; ++kt) {
    if (kt < 63) {  // prefetch next tile; drained by the barrier at loop end
      async16(Kbase + (size_t)(kt + 1) * 64 * DD, &Ks[cur ^ 1][t * 8]);
      async16(Vbase + (size_t)(kt + 1) * 64, &Vs[cur ^ 1][t * 8]);
    }
    const short* Kc = Ks[cur];
    const short* Vc = Vs[cur];
    short* Pw = Ps[w];

    // --- QK^T: S[16 q][64 key] = 4 MFMAs (K=32 = full D) ---
    f32x4 s[4];
#pragma unroll
    for (int nb = 0; nb < 4; ++nb) {
      const int key = nb * 16 + lo;
      const int R = key >> 1;
      const int slot = (((key & 1) << 2) + hi) ^ (R & 7);
      const bf16x8 kf = *(const bf16x8*)(Kc + R * 64 + slot * 8);
      s[nb] = __builtin_amdgcn_mfma_f32_16x16x32_bf16(
          qf, kf, (f32x4){0.f, 0.f, 0.f, 0.f}, 0, 0, 0);
    }

    // --- online softmax (rows live in regs; 16-lane group shares q-rows) ---
#pragma unroll
    for (int r = 0; r < 4; ++r) {
      float mx = fmaxf(fmaxf(s[0][r], s[1][r]), fmaxf(s[2][r], s[3][r]));
      mx = fmaxf(mx, __shfl_xor(mx, 1));
      mx = fmaxf(mx, __shfl_xor(mx, 2));
      mx = fmaxf(mx, __shfl_xor(mx, 4));
      mx = fmaxf(mx, __shfl_xor(mx, 8));
      const float mn = fmaxf(m_run[r], mx);
      const float al = __expf(m_run[r] - mn);
      m_run[r] = mn;
      float sum = 0.f;
#pragma unroll
      for (int nb = 0; nb < 4; ++nb) {
        const float p = __expf(s[nb][r] - mn);
        s[nb][r] = p;
        sum += p;
      }
      sum += __shfl_xor(sum, 1);
      sum += __shfl_xor(sum, 2);
      sum += __shfl_xor(sum, 4);
      sum += __shfl_xor(sum, 8);
      l_run[r] = l_run[r] * al + sum;
      oacc[0][r] *= al;
      oacc[1][r] *= al;
    }

    // --- P -> per-wave LDS (bf16), same-wave RAW (no barrier needed) ---
#pragma unroll
    for (int nb = 0; nb < 4; ++nb) {
#pragma unroll
      for (int r = 0; r < 4; ++r) {
        const int q = hi * 4 + r;
        const int kc = lo + nb * 16;
        const int slot = (kc >> 3) ^ (q & 7);
        Pw[q * 64 + slot * 8 + (kc & 7)] = f2bf(s[nb][r]);
      }
    }

    // --- PV: O[16 q][32 d] += P[16][64] * V[64][32] (4 MFMAs) ---
#pragma unroll
    for (int kb = 0; kb < 2; ++kb) {
      const int chunk = kb * 4 + hi;
      const bf16x8 pa = *(const bf16x8*)(Pw + lo * 64 + (chunk ^ (lo & 7)) * 8);
#pragma unroll
      for (int db = 0; db < 2; ++db) {
        const int drow = db * 16 + lo;
        const bf16x8 vb =
            *(const bf16x8*)(Vc + drow * 64 + (chunk ^ (drow & 7)) * 8);
        oacc[db] = __builtin_amdgcn_mfma_f32_16x16x32_bf16(pa, vb, oacc[db], 0, 0, 0);
      }
    }

    __syncthreads();  // drains prefetch vmcnt + flips buffers for all waves
    cur ^= 1;
  }

  // epilogue: normalize, store fp32 O
  float* Ob = O + ((size_t)b * NN + n0 + w * 16) * DD;
#pragma unroll
  for (int r = 0; r < 4; ++r) {
    const float inv = 1.0f / l_run[r];
#pragma unroll
    for (int db = 0; db < 2; ++db)
      Ob[(hi * 4 + r) * DD + db * 16 + lo] = oacc[db][r] * inv;
  }
}

// ---------------------------------------------------------------------------
// Kernel 3: output projection + residual (unchanged, fp32).
// ---------------------------------------------------------------------------
__global__ __launch_bounds__(256) void proj_kernel(
    const float* __restrict__ O, const float* __restrict__ w_proj,
    const float* __restrict__ b_proj, const float* __restrict__ x,
    float* __restrict__ out) {
  __shared__ float Os[64 * 36];
  const int t = threadIdx.x;
  const int b = blockIdx.x >> 6;
  const int n0 = (blockIdx.x & 63) << 6;
  const float* Obl = O + ((size_t)b * NN + n0) * DD;

#pragma unroll
  for (int p = 0; p < 2; ++p) {
    const int idx = t + 256 * p;
    const int row = idx >> 3, c4 = idx & 7;
    *(float4*)&Os[row * 36 + c4 * 4] = *(const float4*)&Obl[row * DD + c4 * 4];
  }
  __syncthreads();

  const int tokl = t & 63;
  const int cg = __builtin_amdgcn_readfirstlane(t >> 6);

  float ov[DD];
#pragma unroll
  for (int c4 = 0; c4 < 8; ++c4) {
    const float4 v = *(const float4*)&Os[tokl * 36 + c4 * 4];
    ov[c4 * 4 + 0] = v.x;
    ov[c4 * 4 + 1] = v.y;
    ov[c4 * 4 + 2] = v.z;
    ov[c4 * 4 + 3] = v.w;
  }

  const size_t base = (size_t)b * CC * NN + n0 + tokl;
  for (int i = 0; i < 64; ++i) {
    const int c = cg * 64 + i;
    const float* wr = &w_proj[c * DD];
    float acc = b_proj[c];
#pragma unroll
    for (int d = 0; d < DD; ++d) acc += wr[d] * ov[d];
    const size_t off = base + (size_t)c * NN;
    out[off] = acc + x[off];
  }
}

// ---------------------------------------------------------------------------
extern "C" void kernel_launch(void* const* d_in, const int* in_sizes, int n_in,
                              void* d_out, int out_size, void* d_ws, size_t ws_size,
                              hipStream_t stream) {
  const float* x      = (const float*)d_in[0];
  const float* w_qkv  = (const float*)d_in[1];
  const float* b_qkv  = (const float*)d_in[2];
  const float* w_proj = (const float*)d_in[3];
  const float* b_proj = (const float*)d_in[4];
  float* out = (float*)d_out;

  short* qs = (short*)d_ws;
  const size_t BND = (size_t)BB * NN * DD;  // 524288
  short* Qb = qs;
  short* Kb = qs + BND;
  short* Vt = qs + 2 * BND;
  float* O  = (float*)(qs + 3 * BND);  // 3 MB offset, 4B-aligned; O = 2 MB

  const dim3 grid(BB * (NN / 64));  // 256 blocks
  const dim3 block(256);
  qkv_kernel<<<grid, block, 0, stream>>>(x, w_qkv, b_qkv, Qb, Kb, Vt);
  attn_kernel<<<grid, block, 0, stream>>>(Qb, Kb, Vt, O);
  proj_kernel<<<grid, block, 0, stream>>>(O, w_proj, b_proj, x, out);
}

// Round 8
// 180.237 us; speedup vs baseline: 2.4385x; 1.3522x over previous
//
#include <hip/hip_runtime.h>
#include <math.h>

#define CC 256
#define NN 4096
#define DD 32
#define BB 4
#define QK_SCALE 0.17677669529663687f  // 1/sqrt(32)

typedef short bf16x8 __attribute__((ext_vector_type(8)));
typedef float f32x4 __attribute__((ext_vector_type(4)));

__device__ __forceinline__ short f2bf(float f) {  // RNE float->bf16
  unsigned u = __builtin_bit_cast(unsigned, f);
  u += 0x7fffu + ((u >> 16) & 1u);
  return (short)(u >> 16);
}

// ---------------------------------------------------------------------------
// Kernel 1: QKV projection -> bf16 Q (pre-scaled) [B][N][32], K [B][N][32],
// V transposed [B][32][N].  (unchanged from round 5)
// ---------------------------------------------------------------------------
__global__ __launch_bounds__(256) void qkv_kernel(
    const float* __restrict__ x, const float* __restrict__ w_qkv,
    const float* __restrict__ b_qkv, short* __restrict__ Qb,
    short* __restrict__ Kb, short* __restrict__ Vt) {
  __shared__ float xs[CC * 64];  // [c][tok]
  const int t = threadIdx.x;
  const int b = blockIdx.x >> 6;
  const int n0 = (blockIdx.x & 63) << 6;
  const float* xb = x + (size_t)b * CC * NN + n0;

  {
    const int tokl = t & 63, cg = t >> 6;
    for (int i = 0; i < 64; ++i) {
      const int c = cg * 64 + i;
      xs[c * 64 + tokl] = xb[(size_t)c * NN + tokl];
    }
  }
  __syncthreads();

  const int tt = t & 15;
  const int g = t >> 4;
  float acc[6][4];
#pragma unroll
  for (int j = 0; j < 6; ++j) {
    const float bv = b_qkv[g * 6 + j];
#pragma unroll
    for (int r = 0; r < 4; ++r) acc[j][r] = bv;
  }

  for (int cb = 0; cb < CC; cb += 4) {
    float4 xv[4];
#pragma unroll
    for (int q = 0; q < 4; ++q)
      xv[q] = *(const float4*)&xs[(cb + q) * 64 + tt * 4];
#pragma unroll
    for (int j = 0; j < 6; ++j) {
      const float4 wv = *(const float4*)&w_qkv[(g * 6 + j) * CC + cb];
      acc[j][0] += wv.x * xv[0].x + wv.y * xv[1].x + wv.z * xv[2].x + wv.w * xv[3].x;
      acc[j][1] += wv.x * xv[0].y + wv.y * xv[1].y + wv.z * xv[2].y + wv.w * xv[3].y;
      acc[j][2] += wv.x * xv[0].z + wv.y * xv[1].z + wv.z * xv[2].z + wv.w * xv[3].z;
      acc[j][3] += wv.x * xv[0].w + wv.y * xv[1].w + wv.z * xv[2].w + wv.w * xv[3].w;
    }
  }

#pragma unroll
  for (int j = 0; j < 6; ++j) {
    const int d = g * 6 + j;
#pragma unroll
    for (int r = 0; r < 4; ++r) {
      const int tok = n0 + tt * 4 + r;
      const float v = acc[j][r];
      if (d < DD)
        Qb[((size_t)b * NN + tok) * DD + d] = f2bf(v * QK_SCALE);
      else if (d < 2 * DD)
        Kb[((size_t)b * NN + tok) * DD + (d - DD)] = f2bf(v);
      else
        Vt[(size_t)b * DD * NN + (size_t)(d - 2 * DD) * NN + tok] = f2bf(v);
    }
  }
}

// ---------------------------------------------------------------------------
// Kernel 2 (v3): flash attention, KV-split for occupancy.
// Block = (b, 16 q rows); 4 waves each own a disjoint 1024-key range
// (16 tiles of 64), fully independent (no barriers in the loop); partial
// (m,l,O) merged across waves at the end.  Grid = 1024 blocks = 4/CU.
// K/V fragments load DIRECTLY global->VGPR (L2-resident), double-buffered
// in registers via unroll-by-2 with macro-expanded static indexing.
// P round-trips through per-wave swizzled LDS (0 conflicts, measured r5).
// Frag maps: A/B row|col = lane&15, k = (lane>>4)*8+j; C/D col=lane&15,
// row=(lane>>4)*4+reg.
// ---------------------------------------------------------------------------
__global__ __launch_bounds__(256, 4) void attn_kernel(
    const short* __restrict__ Qb, const short* __restrict__ Kb,
    const short* __restrict__ Vt, float* __restrict__ O) {
  __shared__ short Ps[4][1024];        // per-wave P tile (swizzled)
  __shared__ float Pm[4][16], Pl[4][16];
  __shared__ float Po[4][16][32];      // per-wave partial O

  const int t = threadIdx.x;
  const int b = blockIdx.x >> 8;
  const int q0 = (blockIdx.x & 255) << 4;
  const int w = t >> 6;
  const int lane = t & 63;
  const int lo = lane & 15, hi = lane >> 4;

  const short* Kp = Kb + (size_t)b * NN * DD;
  const short* Vp = Vt + (size_t)b * DD * NN;
  short* Pw = Ps[w];

  // Q A-frag (16 rows, held in regs for all tiles; same for all 4 waves)
  const bf16x8 qf =
      *(const bf16x8*)(Qb + ((size_t)b * NN + q0 + lo) * DD + hi * 8);

  f32x4 oacc[2];
  float m_run[4], l_run[4];
#pragma unroll
  for (int r = 0; r < 4; ++r) {
    m_run[r] = -1e30f;
    l_run[r] = 0.f;
    oacc[0][r] = 0.f;
    oacc[1][r] = 0.f;
  }

  const int kbase = w << 10;  // this wave's first key

// load one tile's K/V fragments into named regs (static indexing only)
#define LOADF(kf, vf, key0)                                                   \
  {                                                                           \
    _Pragma("unroll") for (int nb = 0; nb < 4; ++nb)                          \
        kf[nb] = *(const bf16x8*)(Kp + (size_t)((key0) + nb * 16 + lo) * DD + \
                                  hi * 8);                                    \
    _Pragma("unroll") for (int k2 = 0; k2 < 2; ++k2)                          \
        _Pragma("unroll") for (int db = 0; db < 2; ++db)                      \
            vf[k2 * 2 + db] = *(const bf16x8*)(Vp +                           \
                                               (size_t)(db * 16 + lo) * NN +  \
                                               (key0) + k2 * 32 + hi * 8);    \
  }

// process one tile from fragments kf/vf
#define COMPUTE(kf, vf)                                                       \
  {                                                                           \
    f32x4 s[4];                                                               \
    _Pragma("unroll") for (int nb = 0; nb < 4; ++nb)                          \
        s[nb] = __builtin_amdgcn_mfma_f32_16x16x32_bf16(                      \
            qf, kf[nb], (f32x4){0.f, 0.f, 0.f, 0.f}, 0, 0, 0);                \
    _Pragma("unroll") for (int r = 0; r < 4; ++r) {                           \
      float mx = fmaxf(fmaxf(s[0][r], s[1][r]), fmaxf(s[2][r], s[3][r]));     \
      mx = fmaxf(mx, __shfl_xor(mx, 1));                                      \
      mx = fmaxf(mx, __shfl_xor(mx, 2));                                      \
      mx = fmaxf(mx, __shfl_xor(mx, 4));                                      \
      mx = fmaxf(mx, __shfl_xor(mx, 8));                                      \
      const float mn = fmaxf(m_run[r], mx);                                   \
      const float al = __expf(m_run[r] - mn);                                 \
      m_run[r] = mn;                                                          \
      float sum = 0.f;                                                        \
      _Pragma("unroll") for (int nb = 0; nb < 4; ++nb) {                      \
        const float p = __expf(s[nb][r] - mn);                                \
        s[nb][r] = p;                                                         \
        sum += p;                                                             \
      }                                                                       \
      sum += __shfl_xor(sum, 1);                                              \
      sum += __shfl_xor(sum, 2);                                              \
      sum += __shfl_xor(sum, 4);                                              \
      sum += __shfl_xor(sum, 8);                                              \
      l_run[r] = l_run[r] * al + sum;                                         \
      oacc[0][r] *= al;                                                       \
      oacc[1][r] *= al;                                                       \
    }                                                                         \
    _Pragma("unroll") for (int nb = 0; nb < 4; ++nb)                          \
        _Pragma("unroll") for (int r = 0; r < 4; ++r) {                       \
      const int q = hi * 4 + r;                                               \
      const int kc = lo + nb * 16;                                            \
      const int slot = (kc >> 3) ^ (q & 7);                                   \
      Pw[q * 64 + slot * 8 + (kc & 7)] = f2bf(s[nb][r]);                      \
    }                                                                         \
    _Pragma("unroll") for (int k2 = 0; k2 < 2; ++k2) {                        \
      const int chunk = k2 * 4 + hi;                                          \
      const bf16x8 pa =                                                       \
          *(const bf16x8*)(Pw + lo * 64 + (chunk ^ (lo & 7)) * 8);            \
      _Pragma("unroll") for (int db = 0; db < 2; ++db) oacc[db] =             \
          __builtin_amdgcn_mfma_f32_16x16x32_bf16(pa, vf[k2 * 2 + db],        \
                                                  oacc[db], 0, 0, 0);         \
    }                                                                         \
  }

  bf16x8 kfa[4], vfa[4], kfb[4], vfb[4];
  LOADF(kfa, vfa, kbase);
  for (int tt = 0; tt < 16; tt += 2) {
    LOADF(kfb, vfb, kbase + (tt + 1) * 64);
    COMPUTE(kfa, vfa);
    const int nt2 = (tt + 2 < 16) ? tt + 2 : 15;  // tail: load valid, unused
    LOADF(kfa, vfa, kbase + nt2 * 64);
    COMPUTE(kfb, vfb);
  }
#undef LOADF
#undef COMPUTE

  // ---- publish per-wave partials, merge across the 4 KV-splits ----
  if (lo == 0) {
#pragma unroll
    for (int r = 0; r < 4; ++r) {
      Pm[w][hi * 4 + r] = m_run[r];
      Pl[w][hi * 4 + r] = l_run[r];
    }
  }
#pragma unroll
  for (int r = 0; r < 4; ++r) {
    Po[w][hi * 4 + r][lo]      = oacc[0][r];
    Po[w][hi * 4 + r][16 + lo] = oacc[1][r];
  }
  __syncthreads();

  if (w == 0) {
    float* Ob = O + ((size_t)b * NN + q0) * DD;
#pragma unroll
    for (int r = 0; r < 4; ++r) {
      const int row = hi * 4 + r;
      const float m0 = Pm[0][row], m1 = Pm[1][row], m2 = Pm[2][row],
                  m3 = Pm[3][row];
      const float ms = fmaxf(fmaxf(m0, m1), fmaxf(m2, m3));
      const float a0 = __expf(m0 - ms), a1 = __expf(m1 - ms),
                  a2 = __expf(m2 - ms), a3 = __expf(m3 - ms);
      const float ls =
          a0 * Pl[0][row] + a1 * Pl[1][row] + a2 * Pl[2][row] + a3 * Pl[3][row];
      const float inv = 1.0f / ls;
#pragma unroll
      for (int db = 0; db < 2; ++db) {
        const int col = db * 16 + lo;
        const float o = a0 * Po[0][row][col] + a1 * Po[1][row][col] +
                        a2 * Po[2][row][col] + a3 * Po[3][row][col];
        Ob[row * DD + col] = o * inv;
      }
    }
  }
}

// ---------------------------------------------------------------------------
// Kernel 3: output projection + residual (unchanged, fp32).
// ---------------------------------------------------------------------------
__global__ __launch_bounds__(256) void proj_kernel(
    const float* __restrict__ O, const float* __restrict__ w_proj,
    const float* __restrict__ b_proj, const float* __restrict__ x,
    float* __restrict__ out) {
  __shared__ float Os[64 * 36];
  const int t = threadIdx.x;
  const int b = blockIdx.x >> 6;
  const int n0 = (blockIdx.x & 63) << 6;
  const float* Obl = O + ((size_t)b * NN + n0) * DD;

#pragma unroll
  for (int p = 0; p < 2; ++p) {
    const int idx = t + 256 * p;
    const int row = idx >> 3, c4 = idx & 7;
    *(float4*)&Os[row * 36 + c4 * 4] = *(const float4*)&Obl[row * DD + c4 * 4];
  }
  __syncthreads();

  const int tokl = t & 63;
  const int cg = __builtin_amdgcn_readfirstlane(t >> 6);

  float ov[DD];
#pragma unroll
  for (int c4 = 0; c4 < 8; ++c4) {
    const float4 v = *(const float4*)&Os[tokl * 36 + c4 * 4];
    ov[c4 * 4 + 0] = v.x;
    ov[c4 * 4 + 1] = v.y;
    ov[c4 * 4 + 2] = v.z;
    ov[c4 * 4 + 3] = v.w;
  }

  const size_t base = (size_t)b * CC * NN + n0 + tokl;
  for (int i = 0; i < 64; ++i) {
    const int c = cg * 64 + i;
    const float* wr = &w_proj[c * DD];
    float acc = b_proj[c];
#pragma unroll
    for (int d = 0; d < DD; ++d) acc += wr[d] * ov[d];
    const size_t off = base + (size_t)c * NN;
    out[off] = acc + x[off];
  }
}

// ---------------------------------------------------------------------------
extern "C" void kernel_launch(void* const* d_in, const int* in_sizes, int n_in,
                              void* d_out, int out_size, void* d_ws, size_t ws_size,
                              hipStream_t stream) {
  const float* x      = (const float*)d_in[0];
  const float* w_qkv  = (const float*)d_in[1];
  const float* b_qkv  = (const float*)d_in[2];
  const float* w_proj = (const float*)d_in[3];
  const float* b_proj = (const float*)d_in[4];
  float* out = (float*)d_out;

  short* qs = (short*)d_ws;
  const size_t BND = (size_t)BB * NN * DD;  // 524288
  short* Qb = qs;
  short* Kb = qs + BND;
  short* Vt = qs + 2 * BND;
  float* O  = (float*)(qs + 3 * BND);  // 3 MB offset, 4B-aligned; O = 2 MB

  const dim3 block(256);
  qkv_kernel<<<dim3(BB * (NN / 64)), block, 0, stream>>>(x, w_qkv, b_qkv, Qb, Kb, Vt);
  attn_kernel<<<dim3(BB * (NN / 16)), block, 0, stream>>>(Qb, Kb, Vt, O);
  proj_kernel<<<dim3(BB * (NN / 64)), block, 0, stream>>>(O, w_proj, b_proj, x, out);
}

// Round 13
// 162.013 us; speedup vs baseline: 2.7128x; 1.1125x over previous
//
#include <hip/hip_runtime.h>
#include <math.h>

#define CC 256
#define NN 4096
#define DD 32
#define BB 4
#define QK_SCALE 0.17677669529663687f  // 1/sqrt(32)

typedef short bf16x8 __attribute__((ext_vector_type(8)));
typedef float f32x4 __attribute__((ext_vector_type(4)));

__device__ __forceinline__ short f2bf(float f) {  // RNE float->bf16
  unsigned u = __builtin_bit_cast(unsigned, f);
  u += 0x7fffu + ((u >> 16) & 1u);
  return (short)(u >> 16);
}

// ---------------------------------------------------------------------------
// Kernel 1 (v2): QKV projection, occupancy-fixed.
// Grid = B * 256 (16-token tiles) = 1024 blocks (4/CU, 4 waves/SIMD).
// LDS: x tile [256 c][16 tok] fp32 (16 KB). Thread: 2 tokens x 3 d.
// Same c-loop order as v1 -> bit-identical Q/K/V.
// ---------------------------------------------------------------------------
__global__ __launch_bounds__(256) void qkv_kernel(
    const float* __restrict__ x, const float* __restrict__ w_qkv,
    const float* __restrict__ b_qkv, short* __restrict__ Qb,
    short* __restrict__ Kb, short* __restrict__ Vt) {
  __shared__ float xs[CC * 16];  // [c][tok]
  const int t = threadIdx.x;
  const int b = blockIdx.x >> 8;
  const int n0 = (blockIdx.x & 255) << 4;
  const float* xb = x + (size_t)b * CC * NN + n0;

#pragma unroll
  for (int p = 0; p < 16; ++p) {
    const int i = t + 256 * p;
    const int c = i >> 4, tok = i & 15;
    xs[c * 16 + tok] = xb[(size_t)c * NN + tok];
  }
  __syncthreads();

  const int tp = t & 7;  // tokens 2tp, 2tp+1
  const int g = t >> 3;  // d = 3g..3g+2  (g in 0..31)
  float acc[3][2];
#pragma unroll
  for (int j = 0; j < 3; ++j) {
    const float bv = b_qkv[g * 3 + j];
    acc[j][0] = bv;
    acc[j][1] = bv;
  }

  for (int cb = 0; cb < CC; cb += 4) {
    float2 xv[4];
#pragma unroll
    for (int q = 0; q < 4; ++q)
      xv[q] = *(const float2*)&xs[(cb + q) * 16 + tp * 2];
#pragma unroll
    for (int j = 0; j < 3; ++j) {
      const float4 wv = *(const float4*)&w_qkv[(g * 3 + j) * CC + cb];
      acc[j][0] += wv.x * xv[0].x + wv.y * xv[1].x + wv.z * xv[2].x + wv.w * xv[3].x;
      acc[j][1] += wv.x * xv[0].y + wv.y * xv[1].y + wv.z * xv[2].y + wv.w * xv[3].y;
    }
  }

#pragma unroll
  for (int j = 0; j < 3; ++j) {
    const int d = g * 3 + j;
#pragma unroll
    for (int r = 0; r < 2; ++r) {
      const int tok = n0 + tp * 2 + r;
      const float v = acc[j][r];
      if (d < DD)
        Qb[((size_t)b * NN + tok) * DD + d] = f2bf(v * QK_SCALE);
      else if (d < 2 * DD)
        Kb[((size_t)b * NN + tok) * DD + (d - DD)] = f2bf(v);
      else
        Vt[(size_t)b * DD * NN + (size_t)(d - 2 * DD) * NN + tok] = f2bf(v);
    }
  }
}

// ---------------------------------------------------------------------------
// Kernel 2 (v3): flash attention, KV-split. UNCHANGED from round 8
// (58.4 us measured; next round's target).
// ---------------------------------------------------------------------------
__global__ __launch_bounds__(256, 4) void attn_kernel(
    const short* __restrict__ Qb, const short* __restrict__ Kb,
    const short* __restrict__ Vt, float* __restrict__ O) {
  __shared__ short Ps[4][1024];        // per-wave P tile (swizzled)
  __shared__ float Pm[4][16], Pl[4][16];
  __shared__ float Po[4][16][32];      // per-wave partial O

  const int t = threadIdx.x;
  const int b = blockIdx.x >> 8;
  const int q0 = (blockIdx.x & 255) << 4;
  const int w = t >> 6;
  const int lane = t & 63;
  const int lo = lane & 15, hi = lane >> 4;

  const short* Kp = Kb + (size_t)b * NN * DD;
  const short* Vp = Vt + (size_t)b * DD * NN;
  short* Pw = Ps[w];

  const bf16x8 qf =
      *(const bf16x8*)(Qb + ((size_t)b * NN + q0 + lo) * DD + hi * 8);

  f32x4 oacc[2];
  float m_run[4], l_run[4];
#pragma unroll
  for (int r = 0; r < 4; ++r) {
    m_run[r] = -1e30f;
    l_run[r] = 0.f;
    oacc[0][r] = 0.f;
    oacc[1][r] = 0.f;
  }

  const int kbase = w << 10;  // this wave's first key

#define LOADF(kf, vf, key0)                                                   \
  {                                                                           \
    _Pragma("unroll") for (int nb = 0; nb < 4; ++nb)                          \
        kf[nb] = *(const bf16x8*)(Kp + (size_t)((key0) + nb * 16 + lo) * DD + \
                                  hi * 8);                                    \
    _Pragma("unroll") for (int k2 = 0; k2 < 2; ++k2)                          \
        _Pragma("unroll") for (int db = 0; db < 2; ++db)                      \
            vf[k2 * 2 + db] = *(const bf16x8*)(Vp +                           \
                                               (size_t)(db * 16 + lo) * NN +  \
                                               (key0) + k2 * 32 + hi * 8);    \
  }

#define COMPUTE(kf, vf)                                                       \
  {                                                                           \
    f32x4 s[4];                                                               \
    _Pragma("unroll") for (int nb = 0; nb < 4; ++nb)                          \
        s[nb] = __builtin_amdgcn_mfma_f32_16x16x32_bf16(                      \
            qf, kf[nb], (f32x4){0.f, 0.f, 0.f, 0.f}, 0, 0, 0);                \
    _Pragma("unroll") for (int r = 0; r < 4; ++r) {                           \
      float mx = fmaxf(fmaxf(s[0][r], s[1][r]), fmaxf(s[2][r], s[3][r]));     \
      mx = fmaxf(mx, __shfl_xor(mx, 1));                                      \
      mx = fmaxf(mx, __shfl_xor(mx, 2));                                      \
      mx = fmaxf(mx, __shfl_xor(mx, 4));                                      \
      mx = fmaxf(mx, __shfl_xor(mx, 8));                                      \
      const float mn = fmaxf(m_run[r], mx);                                   \
      const float al = __expf(m_run[r] - mn);                                 \
      m_run[r] = mn;                                                          \
      float sum = 0.f;                                                        \
      _Pragma("unroll") for (int nb = 0; nb < 4; ++nb) {                      \
        const float p = __expf(s[nb][r] - mn);                                \
        s[nb][r] = p;                                                         \
        sum += p;                                                             \
      }                                                                       \
      sum += __shfl_xor(sum, 1);                                              \
      sum += __shfl_xor(sum, 2);                                              \
      sum += __shfl_xor(sum, 4);                                              \
      sum += __shfl_xor(sum, 8);                                              \
      l_run[r] = l_run[r] * al + sum;                                         \
      oacc[0][r] *= al;                                                       \
      oacc[1][r] *= al;                                                       \
    }                                                                         \
    _Pragma("unroll") for (int nb = 0; nb < 4; ++nb)                          \
        _Pragma("unroll") for (int r = 0; r < 4; ++r) {                       \
      const int q = hi * 4 + r;                                               \
      const int kc = lo + nb * 16;                                            \
      const int slot = (kc >> 3) ^ (q & 7);                                   \
      Pw[q * 64 + slot * 8 + (kc & 7)] = f2bf(s[nb][r]);                      \
    }                                                                         \
    _Pragma("unroll") for (int k2 = 0; k2 < 2; ++k2) {                        \
      const int chunk = k2 * 4 + hi;                                          \
      const bf16x8 pa =                                                       \
          *(const bf16x8*)(Pw + lo * 64 + (chunk ^ (lo & 7)) * 8);            \
      _Pragma("unroll") for (int db = 0; db < 2; ++db) oacc[db] =             \
          __builtin_amdgcn_mfma_f32_16x16x32_bf16(pa, vf[k2 * 2 + db],        \
                                                  oacc[db], 0, 0, 0);         \
    }                                                                         \
  }

  bf16x8 kfa[4], vfa[4], kfb[4], vfb[4];
  LOADF(kfa, vfa, kbase);
  for (int tt = 0; tt < 16; tt += 2) {
    LOADF(kfb, vfb, kbase + (tt + 1) * 64);
    COMPUTE(kfa, vfa);
    const int nt2 = (tt + 2 < 16) ? tt + 2 : 15;  // tail: load valid, unused
    LOADF(kfa, vfa, kbase + nt2 * 64);
    COMPUTE(kfb, vfb);
  }
#undef LOADF
#undef COMPUTE

  if (lo == 0) {
#pragma unroll
    for (int r = 0; r < 4; ++r) {
      Pm[w][hi * 4 + r] = m_run[r];
      Pl[w][hi * 4 + r] = l_run[r];
    }
  }
#pragma unroll
  for (int r = 0; r < 4; ++r) {
    Po[w][hi * 4 + r][lo]      = oacc[0][r];
    Po[w][hi * 4 + r][16 + lo] = oacc[1][r];
  }
  __syncthreads();

  if (w == 0) {
    float* Ob = O + ((size_t)b * NN + q0) * DD;
#pragma unroll
    for (int r = 0; r < 4; ++r) {
      const int row = hi * 4 + r;
      const float m0 = Pm[0][row], m1 = Pm[1][row], m2 = Pm[2][row],
                  m3 = Pm[3][row];
      const float ms = fmaxf(fmaxf(m0, m1), fmaxf(m2, m3));
      const float a0 = __expf(m0 - ms), a1 = __expf(m1 - ms),
                  a2 = __expf(m2 - ms), a3 = __expf(m3 - ms);
      const float ls =
          a0 * Pl[0][row] + a1 * Pl[1][row] + a2 * Pl[2][row] + a3 * Pl[3][row];
      const float inv = 1.0f / ls;
#pragma unroll
      for (int db = 0; db < 2; ++db) {
        const int col = db * 16 + lo;
        const float o = a0 * Po[0][row][col] + a1 * Po[1][row][col] +
                        a2 * Po[2][row][col] + a3 * Po[3][row][col];
        Ob[row * DD + col] = o * inv;
      }
    }
  }
}

// ---------------------------------------------------------------------------
// Kernel 3 (v2): output projection + residual, occupancy-fixed.
// Grid = B * 64 (token tiles) * 4 (channel quarters) = 1024 blocks (4/CU).
// Block: 64 tokens x 64 channels; wave-uniform 16-channel group preserved
// (scalar w_proj loads); same MAC order -> bit-identical out.
// ---------------------------------------------------------------------------
__global__ __launch_bounds__(256) void proj_kernel(
    const float* __restrict__ O, const float* __restrict__ w_proj,
    const float* __restrict__ b_proj, const float* __restrict__ x,
    float* __restrict__ out) {
  __shared__ float Os[64 * 36];
  const int t = threadIdx.x;
  const int qset = blockIdx.x & 3;
  const int n0 = ((blockIdx.x >> 2) & 63) << 6;
  const int b = blockIdx.x >> 8;
  const float* Obl = O + ((size_t)b * NN + n0) * DD;

#pragma unroll
  for (int p = 0; p < 2; ++p) {
    const int idx = t + 256 * p;
    const int row = idx >> 3, c4 = idx & 7;
    *(float4*)&Os[row * 36 + c4 * 4] = *(const float4*)&Obl[row * DD + c4 * 4];
  }
  __syncthreads();

  const int tokl = t & 63;
  const int cg = __builtin_amdgcn_readfirstlane(t >> 6);  // 0..3, wave-uniform

  float ov[DD];
#pragma unroll
  for (int c4 = 0; c4 < 8; ++c4) {
    const float4 v = *(const float4*)&Os[tokl * 36 + c4 * 4];
    ov[c4 * 4 + 0] = v.x;
    ov[c4 * 4 + 1] = v.y;
    ov[c4 * 4 + 2] = v.z;
    ov[c4 * 4 + 3] = v.w;
  }

  const size_t base = (size_t)b * CC * NN + n0 + tokl;
  const int c0 = qset * 64 + cg * 16;
  for (int i = 0; i < 16; ++i) {
    const int c = c0 + i;
    const float* wr = &w_proj[c * DD];
    float acc = b_proj[c];
#pragma unroll
    for (int d = 0; d < DD; ++d) acc += wr[d] * ov[d];
    const size_t off = base + (size_t)c * NN;
    out[off] = acc + x[off];
  }
}

// ---------------------------------------------------------------------------
extern "C" void kernel_launch(void* const* d_in, const int* in_sizes, int n_in,
                              void* d_out, int out_size, void* d_ws, size_t ws_size,
                              hipStream_t stream) {
  const float* x      = (const float*)d_in[0];
  const float* w_qkv  = (const float*)d_in[1];
  const float* b_qkv  = (const float*)d_in[2];
  const float* w_proj = (const float*)d_in[3];
  const float* b_proj = (const float*)d_in[4];
  float* out = (float*)d_out;

  short* qs = (short*)d_ws;
  const size_t BND = (size_t)BB * NN * DD;  // 524288
  short* Qb = qs;
  short* Kb = qs + BND;
  short* Vt = qs + 2 * BND;
  float* O  = (float*)(qs + 3 * BND);  // 3 MB offset, 4B-aligned; O = 2 MB

  const dim3 block(256);
  qkv_kernel<<<dim3(BB * (NN / 16)), block, 0, stream>>>(x, w_qkv, b_qkv, Qb, Kb, Vt);
  attn_kernel<<<dim3(BB * (NN / 16)), block, 0, stream>>>(Qb, Kb, Vt, O);
  proj_kernel<<<dim3(BB * (NN / 64) * 4), block, 0, stream>>>(O, w_proj, b_proj, x, out);
}